// Round 4
// baseline (175.704 us; speedup 1.0000x reference)
//
#include <hip/hip_runtime.h>
#include <math.h>

#define PP 4096   // P = H*W
#define CC 256    // channels
#define NN 2      // batch

typedef __attribute__((ext_vector_type(8))) short short8;
typedef __attribute__((ext_vector_type(4))) float f32x4;

__device__ __forceinline__ short f2bf(float x) {
    union { float f; unsigned u; } un; un.f = x;
    unsigned r = un.u + 0x7fffu + ((un.u >> 16) & 1u);  // RNE to bf16
    return (short)(r >> 16);
}

__device__ __forceinline__ void gld_lds16(const short* g, short* l) {
    __builtin_amdgcn_global_load_lds(
        (const __attribute__((address_space(1))) unsigned int*)g,
        (__attribute__((address_space(3))) unsigned int*)l, 16, 0, 0);
}

// ---- kernel 1: meanT[c] = mean over (n,p) of T; also init stats arrays ----
__global__ __launch_bounds__(256) void mean_kernel(const float* __restrict__ T,
                                                   float* __restrict__ meanT,
                                                   unsigned* __restrict__ mn_enc,
                                                   float* __restrict__ S,
                                                   float* __restrict__ diagw) {
    int c = blockIdx.x, tid = threadIdx.x;
    float s = 0.f;
    for (int n = 0; n < NN; n++)
        for (int p = tid; p < PP; p += 256)
            s += T[(size_t)(n * CC + c) * PP + p];
    __shared__ float red[256];
    red[tid] = s; __syncthreads();
    for (int st = 128; st > 0; st >>= 1) {
        if (tid < st) red[tid] += red[tid + st];
        __syncthreads();
    }
    if (tid == 0) meanT[c] = red[0] * (1.0f / (NN * PP));
    // init stats: 256 blocks x 32 entries = NN*PP = 8192
    int base = blockIdx.x * 32;
    if (tid < 32) {
        mn_enc[base + tid] = 0xFFFFFFFFu;  // +inf in monotone-uint encoding
        S[base + tid] = 0.f;
        diagw[base + tid] = 0.f;
    }
}

// ---- kernel 2: center by meanT, L2-normalize over C, write bf16 transposed [n][p][c] ----
__global__ __launch_bounds__(256) void normalize_kernel(const float* __restrict__ I,
                                                        const float* __restrict__ T,
                                                        const float* __restrict__ meanT,
                                                        short* __restrict__ InT,
                                                        short* __restrict__ TnT) {
    int pc = blockIdx.x * 32;      // 32 positions per block
    int n = blockIdx.y;
    int which = blockIdx.z;        // 0: I -> InT, 1: T -> TnT
    const float* X = which ? T : I;
    short* Y = which ? TnT : InT;

    __shared__ float tile[CC][33];   // [c][p_local], padded
    __shared__ float red[8][32];
    __shared__ float invn[32];

    int tid = threadIdx.x;
    int pl = tid & 31, c0 = tid >> 5;   // 8 c-groups x 32 p
    float sq = 0.f;
    for (int c = c0; c < CC; c += 8) {
        float v = X[(size_t)(n * CC + c) * PP + pc + pl] - meanT[c];
        tile[c][pl] = v;
        sq += v * v;
    }
    red[c0][pl] = sq;
    __syncthreads();
    if (tid < 32) {
        float s = 0.f;
        for (int k = 0; k < 8; k++) s += red[k][tid];
        invn[tid] = 1.0f / sqrtf(s);
    }
    __syncthreads();
    // vectorized write: 2 channels per thread, 2 rows per iteration (4B stores)
    for (int rr = 0; rr < 32; rr += 2) {
        int r = rr + (tid >> 7);
        int c2 = (tid & 127) * 2;
        float v0 = tile[c2][r] * invn[r];
        float v1 = tile[c2 + 1][r] * invn[r];
        unsigned pack = ((unsigned)(unsigned short)f2bf(v1) << 16) |
                        (unsigned)(unsigned short)f2bf(v0);
        *(unsigned*)&Y[(size_t)(n * PP + pc + r) * CC + c2] = pack;
    }
}

// ---- kernel 3: single NT-GEMM pass. dot[q,p] = sum_c TnT[q][c]*InT[p][c].
// 128x128 tile, BK=64, 8 waves (each 32x64 via 2x4 16x16x32 MFMA) -> small acc
// (32 AGPR) for ~16 waves/CU occupancy. global_load_lds 16B staging, XOR swizzle
// (slot s of row r holds global chunk s^(r&7)): coalesced 128B segments + 2-way-max
// LDS aliasing (free). Stores dot to ws (f32, exact) + column-min -> atomicMin.
__global__ __launch_bounds__(512) void gemm_min_kernel(const short* __restrict__ TnT,
                                                       const short* __restrict__ InT,
                                                       float* __restrict__ dot,
                                                       unsigned* __restrict__ mn_enc) {
    const int n = blockIdx.z;
    const short* __restrict__ A = TnT + (size_t)n * PP * CC;  // A[q*CC + c]
    const short* __restrict__ B = InT + (size_t)n * PP * CC;  // B[p*CC + c]
    float* __restrict__ dotn = dot + (size_t)n * PP * PP;
    const int q0 = blockIdx.y * 128, p0 = blockIdx.x * 128;

    __shared__ __align__(16) short As[128 * 64];  // 16 KB
    __shared__ __align__(16) short Bs[128 * 64];  // 16 KB
    __shared__ float red[8][64];

    const int tid = threadIdx.x;
    const int l = tid & 63, wv = tid >> 6;
    const int lm = l & 15, quad = l >> 4;
    const int wr = (wv & 3) * 32, wc = (wv >> 2) * 64;  // wave tile: 32 rows x 64 cols

    // staging: issue t covers rows t*64 + (tid>>3), slot tid&7;
    // global chunk = slot ^ (row&7); LDS dest lane-order contiguous (DMA rule)
    const int srow = tid >> 3;                       // 0..63
    const int gk = ((tid & 7) ^ (srow & 7)) * 8;     // (row+64)&7 == row&7
    const short* Ag = A + (size_t)(q0 + srow) * CC + gk;
    const short* Bg = B + (size_t)(p0 + srow) * CC + gk;
    short* Al = As + tid * 8;
    short* Bl = Bs + tid * 8;

    f32x4 acc[2][4] = {};

    for (int k0 = 0; k0 < CC; k0 += 64) {
        __syncthreads();  // previous iter's LDS reads done
        gld_lds16(Ag + k0, Al);
        gld_lds16(Ag + 64 * CC + k0, Al + 4096);
        gld_lds16(Bg + k0, Bl);
        gld_lds16(Bg + 64 * CC + k0, Bl + 4096);
        __syncthreads();  // drains vmcnt(0): staged data visible

#pragma unroll
        for (int ksub = 0; ksub < 2; ksub++) {
            const int c = ksub * 4 + quad;  // logical 8-elem k-chunk
            short8 a[2], b[4];
#pragma unroll
            for (int i = 0; i < 2; i++)
                a[i] = *(const short8*)&As[(wr + i * 16 + lm) * 64 + (c ^ (lm & 7)) * 8];
#pragma unroll
            for (int j = 0; j < 4; j++)
                b[j] = *(const short8*)&Bs[(wc + j * 16 + lm) * 64 + (c ^ (lm & 7)) * 8];
#pragma unroll
            for (int i = 0; i < 2; i++)
#pragma unroll
                for (int j = 0; j < 4; j++)
                    acc[i][j] = __builtin_amdgcn_mfma_f32_16x16x32_bf16(a[i], b[j], acc[i][j], 0, 0, 0);
        }
    }

    // C/D layout: col = lm, row = quad*4 + reg. Store dot (f32 exact) + column min.
#pragma unroll
    for (int j = 0; j < 4; j++) {
        float m = 3.4e38f;
#pragma unroll
        for (int i = 0; i < 2; i++)
#pragma unroll
            for (int e = 0; e < 4; e++) {
                float v = acc[i][j][e];
                m = fminf(m, (1.0f - v) * 0.5f);
                int row = q0 + wr + i * 16 + quad * 4 + e;
                int col = p0 + wc + j * 16 + lm;
                dotn[(size_t)row * PP + col] = v;
            }
        m = fminf(m, __shfl_xor(m, 16));
        m = fminf(m, __shfl_xor(m, 32));
        if (quad == 0) red[wv][j * 16 + lm] = m;  // wave's 32-row min for its 64 cols
    }
    __syncthreads();
    if (tid < 128) {
        int grp = tid >> 6, idx = tid & 63;  // grp 0: waves 0-3 (cols 0-63); grp 1: waves 4-7
        float m = fminf(fminf(red[grp * 4 + 0][idx], red[grp * 4 + 1][idx]),
                        fminf(red[grp * 4 + 2][idx], red[grp * 4 + 3][idx]));
        unsigned u = __float_as_uint(m);
        u = (u & 0x80000000u) ? ~u : (u | 0x80000000u);  // monotone encoding
        atomicMin(&mn_enc[n * PP + p0 + tid], u);
    }
}

// ---- kernel 4: streaming column reduce over stored dot ----
// w = exp(10 - raw*10/(mn+eps)), raw=(1-dot)/2; column sum -> atomicAdd(S);
// diagonal -> diagw. grid (16 p-tiles, 32 q-chunks, NN); fully coalesced reads.
__global__ __launch_bounds__(256) void col_reduce(const float* __restrict__ dot,
                                                  const unsigned* __restrict__ mn_enc,
                                                  float* __restrict__ S,
                                                  float* __restrict__ diagw) {
    const int p = blockIdx.x * 256 + threadIdx.x;
    const int q0 = blockIdx.y * 128;
    const int n = blockIdx.z;
    const float* __restrict__ dp = dot + (size_t)n * PP * PP;

    unsigned e = mn_enc[n * PP + p];
    unsigned u = (e & 0x80000000u) ? (e & 0x7fffffffu) : ~e;  // decode
    float mnv = __uint_as_float(u);
    float inv = 10.0f / (mnv + 1e-5f);

    float s = 0.f;
#pragma unroll 8
    for (int q = q0; q < q0 + 128; q++) {
        float v = dp[(size_t)q * PP + p];
        float raw = (1.0f - v) * 0.5f;
        float w = expf(10.0f - raw * inv);
        s += w;
        if (q == p) diagw[n * PP + p] = w;  // unique writer
    }
    atomicAdd(&S[n * PP + p], s);
}

// ---- kernel 5: loss = mean_n -log(0.5 + 0.5 * mean_q(diagw/S)); n parallel ----
__global__ __launch_bounds__(1024) void finalize_kernel(const float* __restrict__ S,
                                                        const float* __restrict__ diagw,
                                                        float* __restrict__ out) {
    __shared__ float red[1024];
    int tid = threadIdx.x;
    int n = tid >> 9, t = tid & 511;
    float s = 0.f;
    for (int i = t; i < PP; i += 512)
        s += diagw[n * PP + i] / S[n * PP + i];
    red[tid] = s; __syncthreads();
    for (int st = 256; st > 0; st >>= 1) {
        if (t < st) red[n * 512 + t] += red[n * 512 + t + st];
        __syncthreads();
    }
    if (tid == 0) {
        float m0 = 0.5f + 0.5f * (red[0] / (float)PP);
        float m1 = 0.5f + 0.5f * (red[512] / (float)PP);
        out[0] = 0.5f * (-logf(m0) - logf(m1));
    }
}

extern "C" void kernel_launch(void* const* d_in, const int* in_sizes, int n_in,
                              void* d_out, int out_size, void* d_ws, size_t ws_size,
                              hipStream_t stream) {
    const float* I = (const float*)d_in[0];
    const float* T = (const float*)d_in[1];
    float* out = (float*)d_out;

    char* ws = (char*)d_ws;
    const size_t SZ_BF = (size_t)NN * PP * CC * sizeof(short);  // 4 MB each
    short* InT = (short*)ws;
    short* TnT = (short*)(ws + SZ_BF);
    float* meanT = (float*)(ws + 2 * SZ_BF);               // 1 KB
    unsigned* mn = (unsigned*)(ws + 2 * SZ_BF + 32768);    // 32 KB
    float* S = (float*)(ws + 2 * SZ_BF + 2 * 32768);       // 32 KB
    float* diagw = (float*)(ws + 2 * SZ_BF + 3 * 32768);   // 32 KB
    float* dot = (float*)(ws + (size_t)16 * 1024 * 1024);  // 134.2 MB (ws is 268 MB)

    mean_kernel<<<CC, 256, 0, stream>>>(T, meanT, mn, S, diagw);
    normalize_kernel<<<dim3(PP / 32, NN, 2), 256, 0, stream>>>(I, T, meanT, InT, TnT);
    gemm_min_kernel<<<dim3(PP / 128, PP / 128, NN), 512, 0, stream>>>(TnT, InT, dot, mn);
    col_reduce<<<dim3(PP / 256, PP / 128, NN), 256, 0, stream>>>(dot, mn, S, diagw);
    finalize_kernel<<<1, 1024, 0, stream>>>(S, diagw, out);
}

// Round 5
// 130.404 us; speedup vs baseline: 1.3474x; 1.3474x over previous
//
#include <hip/hip_runtime.h>
#include <math.h>

#define PP 4096   // P = H*W
#define CC 256    // channels
#define NN 2      // batch

typedef __attribute__((ext_vector_type(8))) short short8;
typedef __attribute__((ext_vector_type(4))) float f32x4;

__device__ __forceinline__ short f2bf(float x) {
    union { float f; unsigned u; } un; un.f = x;
    unsigned r = un.u + 0x7fffu + ((un.u >> 16) & 1u);  // RNE to bf16
    return (short)(r >> 16);
}

__device__ __forceinline__ void gld_lds16(const short* g, short* l) {
    __builtin_amdgcn_global_load_lds(
        (const __attribute__((address_space(1))) unsigned int*)g,
        (__attribute__((address_space(3))) unsigned int*)l, 16, 0, 0);
}

// ---- kernel 1: meanT[c] = mean over (n,p) of T; also init stats arrays ----
__global__ __launch_bounds__(256) void mean_kernel(const float* __restrict__ T,
                                                   float* __restrict__ meanT,
                                                   unsigned* __restrict__ mn_enc,
                                                   float* __restrict__ S,
                                                   float* __restrict__ diagw) {
    int c = blockIdx.x, tid = threadIdx.x;
    float s = 0.f;
    for (int n = 0; n < NN; n++)
        for (int p = tid; p < PP; p += 256)
            s += T[(size_t)(n * CC + c) * PP + p];
    __shared__ float red[256];
    red[tid] = s; __syncthreads();
    for (int st = 128; st > 0; st >>= 1) {
        if (tid < st) red[tid] += red[tid + st];
        __syncthreads();
    }
    if (tid == 0) meanT[c] = red[0] * (1.0f / (NN * PP));
    // init stats: 256 blocks x 32 entries = NN*PP = 8192
    int base = blockIdx.x * 32;
    if (tid < 32) {
        mn_enc[base + tid] = 0xFFFFFFFFu;  // +inf in monotone-uint encoding
        S[base + tid] = 0.f;
        diagw[base + tid] = 0.f;
    }
}

// ---- kernel 2: center by meanT, L2-normalize over C, write bf16 transposed [n][p][c] ----
__global__ __launch_bounds__(256) void normalize_kernel(const float* __restrict__ I,
                                                        const float* __restrict__ T,
                                                        const float* __restrict__ meanT,
                                                        short* __restrict__ InT,
                                                        short* __restrict__ TnT) {
    int pc = blockIdx.x * 32;      // 32 positions per block
    int n = blockIdx.y;
    int which = blockIdx.z;        // 0: I -> InT, 1: T -> TnT
    const float* X = which ? T : I;
    short* Y = which ? TnT : InT;

    __shared__ float tile[CC][33];   // [c][p_local], padded
    __shared__ float red[8][32];
    __shared__ float invn[32];

    int tid = threadIdx.x;
    int pl = tid & 31, c0 = tid >> 5;   // 8 c-groups x 32 p
    float sq = 0.f;
    for (int c = c0; c < CC; c += 8) {
        float v = X[(size_t)(n * CC + c) * PP + pc + pl] - meanT[c];
        tile[c][pl] = v;
        sq += v * v;
    }
    red[c0][pl] = sq;
    __syncthreads();
    if (tid < 32) {
        float s = 0.f;
        for (int k = 0; k < 8; k++) s += red[k][tid];
        invn[tid] = 1.0f / sqrtf(s);
    }
    __syncthreads();
    // vectorized write: 2 channels per thread, 2 rows per iteration (4B stores)
    for (int rr = 0; rr < 32; rr += 2) {
        int r = rr + (tid >> 7);
        int c2 = (tid & 127) * 2;
        float v0 = tile[c2][r] * invn[r];
        float v1 = tile[c2 + 1][r] * invn[r];
        unsigned pack = ((unsigned)(unsigned short)f2bf(v1) << 16) |
                        (unsigned)(unsigned short)f2bf(v0);
        *(unsigned*)&Y[(size_t)(n * PP + pc + r) * CC + c2] = pack;
    }
}

// ---- kernels 3/4: NT-GEMM dot[q,p] = sum_c TnT[q][c]*InT[p][c], fused col stats ----
// 128x128 tile, BK=64, 8 waves (each 32x64 via 2x4 16x16x32 MFMA -> 32 AGPR acc).
// __launch_bounds__(512,6): regs <= 85 -> 6 waves/SIMD; LDS 34 KB -> 3 blocks/CU.
// global_load_lds 16B staging, XOR swizzle (slot s of row r holds chunk s^(r&7)):
// coalesced 128B global segments + 2-way-max LDS aliasing (free per m136).
// MODE 0: column (over q) min of raw=(1-dot)/2 -> atomicMin(mn_enc) [monotone uint]
// MODE 1: w = exp2(14.427 - raw*inv2); column sum -> atomicAdd(S); diag -> diagw
template <int MODE>
__global__ __launch_bounds__(512, 6) void cx_gemm(const short* __restrict__ TnT,
                                                  const short* __restrict__ InT,
                                                  unsigned* __restrict__ mn_enc,
                                                  float* __restrict__ S,
                                                  float* __restrict__ diagw) {
    const int n = blockIdx.z;
    const short* __restrict__ A = TnT + (size_t)n * PP * CC;  // A[q*CC + c]
    const short* __restrict__ B = InT + (size_t)n * PP * CC;  // B[p*CC + c]
    const int q0 = blockIdx.y * 128, p0 = blockIdx.x * 128;

    __shared__ __align__(16) short As[128 * 64];  // 16 KB
    __shared__ __align__(16) short Bs[128 * 64];  // 16 KB
    __shared__ float red[8][64];                  // 2 KB

    const int tid = threadIdx.x;
    const int l = tid & 63, wv = tid >> 6;
    const int lm = l & 15, quad = l >> 4;
    const int wr = (wv & 3) * 32, wc = (wv >> 2) * 64;  // wave tile: 32 rows x 64 cols

    // staging: issue t covers rows t*64 + (tid>>3), slot tid&7;
    // global chunk = slot ^ (row&7); LDS dest lane-order contiguous (DMA rule)
    const int srow = tid >> 3;                       // 0..63
    const int gk = ((tid & 7) ^ (srow & 7)) * 8;     // (row+64)&7 == row&7
    const short* Ag = A + (size_t)(q0 + srow) * CC + gk;
    const short* Bg = B + (size_t)(p0 + srow) * CC + gk;
    short* Al = As + tid * 8;
    short* Bl = Bs + tid * 8;

    f32x4 acc[2][4] = {};

    for (int k0 = 0; k0 < CC; k0 += 64) {
        __syncthreads();  // previous iter's LDS reads done
        gld_lds16(Ag + k0, Al);
        gld_lds16(Ag + 64 * CC + k0, Al + 4096);
        gld_lds16(Bg + k0, Bl);
        gld_lds16(Bg + 64 * CC + k0, Bl + 4096);
        __syncthreads();  // drains vmcnt(0): staged data visible

#pragma unroll
        for (int ksub = 0; ksub < 2; ksub++) {
            const int c = ksub * 4 + quad;  // logical 8-elem k-chunk
            short8 a[2], b[4];
#pragma unroll
            for (int i = 0; i < 2; i++)
                a[i] = *(const short8*)&As[(wr + i * 16 + lm) * 64 + (c ^ (lm & 7)) * 8];
#pragma unroll
            for (int j = 0; j < 4; j++)
                b[j] = *(const short8*)&Bs[(wc + j * 16 + lm) * 64 + (c ^ (lm & 7)) * 8];
#pragma unroll
            for (int i = 0; i < 2; i++)
#pragma unroll
                for (int j = 0; j < 4; j++)
                    acc[i][j] = __builtin_amdgcn_mfma_f32_16x16x32_bf16(a[i], b[j], acc[i][j], 0, 0, 0);
        }
    }

    // C/D layout: col = lm, row = quad*4 + reg (within each 16x16 tile)
    if (MODE == 0) {
#pragma unroll
        for (int j = 0; j < 4; j++) {
            float m = 3.4e38f;
#pragma unroll
            for (int i = 0; i < 2; i++)
#pragma unroll
                for (int e = 0; e < 4; e++)
                    m = fminf(m, (1.0f - acc[i][j][e]) * 0.5f);
            m = fminf(m, __shfl_xor(m, 16));
            m = fminf(m, __shfl_xor(m, 32));
            if (quad == 0) red[wv][j * 16 + lm] = m;  // wave's 32-row min, 64 cols
        }
        __syncthreads();
        if (tid < 128) {
            int grp = tid >> 6, idx = tid & 63;  // grp 0: waves 0-3; grp 1: waves 4-7
            float m = fminf(fminf(red[grp * 4 + 0][idx], red[grp * 4 + 1][idx]),
                            fminf(red[grp * 4 + 2][idx], red[grp * 4 + 3][idx]));
            unsigned u = __float_as_uint(m);
            u = (u & 0x80000000u) ? ~u : (u | 0x80000000u);  // monotone encoding
            atomicMin(&mn_enc[n * PP + p0 + tid], u);
        }
    } else {
#pragma unroll
        for (int j = 0; j < 4; j++) {
            const int col = p0 + wc + j * 16 + lm;  // global p
            unsigned e = mn_enc[n * PP + col];
            unsigned u = (e & 0x80000000u) ? (e & 0x7fffffffu) : ~e;  // decode
            float mnv = __uint_as_float(u);
            // w = exp(10 - 10*raw/(mn+eps)) = exp2(14.4269504 - raw*inv2)
            float inv2 = 14.4269504f / (mnv + 1e-5f);
            float s = 0.f;
#pragma unroll
            for (int i = 0; i < 2; i++)
#pragma unroll
                for (int e2 = 0; e2 < 4; e2++) {
                    float raw = (1.0f - acc[i][j][e2]) * 0.5f;
                    float w = exp2f(fmaf(raw, -inv2, 14.4269504f));
                    s += w;
                    int q = q0 + wr + i * 16 + quad * 4 + e2;  // global q
                    if (q == col) diagw[n * PP + q] = w;       // unique writer
                }
            s += __shfl_xor(s, 16);
            s += __shfl_xor(s, 32);
            if (quad == 0) red[wv][j * 16 + lm] = s;
        }
        __syncthreads();
        if (tid < 128) {
            int grp = tid >> 6, idx = tid & 63;
            float s = red[grp * 4 + 0][idx] + red[grp * 4 + 1][idx] +
                      red[grp * 4 + 2][idx] + red[grp * 4 + 3][idx];
            atomicAdd(&S[n * PP + p0 + tid], s);
        }
    }
}

// ---- kernel 5: loss = mean_n -log(0.5 + 0.5 * mean_q(diagw/S)); n parallel ----
__global__ __launch_bounds__(1024) void finalize_kernel(const float* __restrict__ S,
                                                        const float* __restrict__ diagw,
                                                        float* __restrict__ out) {
    __shared__ float red[1024];
    int tid = threadIdx.x;
    int n = tid >> 9, t = tid & 511;
    float s = 0.f;
    for (int i = t; i < PP; i += 512)
        s += diagw[n * PP + i] / S[n * PP + i];
    red[tid] = s; __syncthreads();
    for (int st = 256; st > 0; st >>= 1) {
        if (t < st) red[n * 512 + t] += red[n * 512 + t + st];
        __syncthreads();
    }
    if (tid == 0) {
        float m0 = 0.5f + 0.5f * (red[0] / (float)PP);
        float m1 = 0.5f + 0.5f * (red[512] / (float)PP);
        out[0] = 0.5f * (-logf(m0) - logf(m1));
    }
}

extern "C" void kernel_launch(void* const* d_in, const int* in_sizes, int n_in,
                              void* d_out, int out_size, void* d_ws, size_t ws_size,
                              hipStream_t stream) {
    const float* I = (const float*)d_in[0];
    const float* T = (const float*)d_in[1];
    float* out = (float*)d_out;

    char* ws = (char*)d_ws;
    const size_t SZ_BF = (size_t)NN * PP * CC * sizeof(short);  // 4 MB each
    short* InT = (short*)ws;
    short* TnT = (short*)(ws + SZ_BF);
    float* meanT = (float*)(ws + 2 * SZ_BF);               // 1 KB
    unsigned* mn = (unsigned*)(ws + 2 * SZ_BF + 32768);    // 32 KB
    float* S = (float*)(ws + 2 * SZ_BF + 2 * 32768);       // 32 KB
    float* diagw = (float*)(ws + 2 * SZ_BF + 3 * 32768);   // 32 KB

    mean_kernel<<<CC, 256, 0, stream>>>(T, meanT, mn, S, diagw);
    normalize_kernel<<<dim3(PP / 32, NN, 2), 256, 0, stream>>>(I, T, meanT, InT, TnT);
    cx_gemm<0><<<dim3(PP / 128, PP / 128, NN), 512, 0, stream>>>(TnT, InT, mn, S, diagw);
    cx_gemm<1><<<dim3(PP / 128, PP / 128, NN), 512, 0, stream>>>(TnT, InT, mn, S, diagw);
    finalize_kernel<<<1, 1024, 0, stream>>>(S, diagw, out);
}